// Round 4
// baseline (1448.669 us; speedup 1.0000x reference)
//
#include <hip/hip_runtime.h>

typedef long long ll;
typedef unsigned int uint;
typedef unsigned short ushort;
typedef __attribute__((ext_vector_type(8))) short short8;
typedef __attribute__((ext_vector_type(4))) float floatx4;

#define NEGV -1e9f

// ---------------- static scratch ----------------
// float offsets:
//  gx 0 (4194304) | glnx 4194304 | gkx 8388608 (262144) | glnk 8650752
//  gcl 8912896 (1024) | glnc 8913920
//  gqx 8914944 (4194304 fp32 Q) | gkvh = gqx+4194304 (8388608 ushort KV bf16)
//  gqk 21497856 (786432) | gqc 22284288 (3072)
//  gko 26481664 (262144) | gco 26743808 (1024)
//  gsc 26744832 (ushort alias, 16777216 us) | gkd 43522048 (partials)
//  gh 60299264 (16777216) | grdT 77076480 (2097152)
//  wts 79173632 (3145728 fl) | glnxh 82319360 | glnkh 84416512
//  glnch 84547584 | gaoh 84548096
__device__ float g_buf[86645248UL];

__device__ __forceinline__ ushort f2bf(float f) {
  uint u = __float_as_uint(f);
  u += 0x7fffu + ((u >> 16) & 1u);
  return (ushort)(u >> 16);
}
__device__ __forceinline__ uint pack2(float lo, float hi) {
  return (uint)f2bf(lo) | ((uint)f2bf(hi) << 16);
}
__device__ __forceinline__ float bf2f(ushort u) {
  return __uint_as_float((uint)u << 16);
}

// ---------------- reductions ----------------
__device__ __forceinline__ float wave_sum(float v) {
#pragma unroll
  for (int o = 1; o < 64; o <<= 1) v += __shfl_xor(v, o, 64);
  return v;
}
__device__ __forceinline__ float wave_max(float v) {
#pragma unroll
  for (int o = 1; o < 64; o <<= 1) v = fmaxf(v, __shfl_xor(v, o, 64));
  return v;
}
__device__ __forceinline__ float block_sum(float v, float* red) {
  v = wave_sum(v);
  if ((threadIdx.x & 63) == 0) red[threadIdx.x >> 6] = v;
  __syncthreads();
  float r = red[0] + red[1] + red[2] + red[3];
  __syncthreads();
  return r;
}
__device__ __forceinline__ float block_max(float v, float* red) {
  v = wave_max(v);
  if ((threadIdx.x & 63) == 0) red[threadIdx.x >> 6] = v;
  __syncthreads();
  float r = fmaxf(fmaxf(red[0], red[1]), fmaxf(red[2], red[3]));
  __syncthreads();
  return r;
}

// ---------------- LayerNorm (rows of 512), fp32 (optional) + bf16 out ------
__global__ __launch_bounds__(256) void ln_kernel(
    const float* __restrict__ in, float* __restrict__ out,
    ushort* __restrict__ outh, const float* __restrict__ gg,
    const float* __restrict__ bb) {
  __shared__ float red[4];
  size_t row = blockIdx.x;
  int tid = threadIdx.x;
  const float* p = in + row * 512;
  float v0 = p[tid], v1 = p[tid + 256];
  float mu = block_sum(v0 + v1, red) * (1.0f / 512.0f);
  float d0 = v0 - mu, d1 = v1 - mu;
  float var = block_sum(d0 * d0 + d1 * d1, red) * (1.0f / 512.0f);
  float rstd = rsqrtf(var + 1e-5f);
  float r0 = d0 * rstd * gg[tid] + bb[tid];
  float r1 = d1 * rstd * gg[tid + 256] + bb[tid + 256];
  if (out) {
    out[row * 512 + tid] = r0;
    out[row * 512 + tid + 256] = r1;
  }
  outh[row * 512 + tid] = f2bf(r0);
  outh[row * 512 + tid + 256] = f2bf(r1);
}

// ---------------- generic fp32 batched transpose ----------------
__global__ void tposef(const float* __restrict__ src, float* __restrict__ dst,
                       int R, int C) {
  __shared__ float tile[32][33];
  int z = blockIdx.z;
  int c0 = blockIdx.x * 32, r0 = blockIdx.y * 32;
  int tx = threadIdx.x, ty = threadIdx.y;
  size_t base = (size_t)z * R * C;
#pragma unroll
  for (int k = 0; k < 4; ++k)
    tile[ty + 8 * k][tx] = src[base + (size_t)(r0 + ty + 8 * k) * C + c0 + tx];
  __syncthreads();
#pragma unroll
  for (int k = 0; k < 4; ++k)
    dst[base + (size_t)(c0 + ty + 8 * k) * R + r0 + tx] = tile[tx][ty + 8 * k];
}

// ---------------- bf16 (Z,R,C) -> fp32 (Z,C,R) transpose (amaps) ----------
__global__ void tposeh2f(const ushort* __restrict__ src,
                         float* __restrict__ dst, int R, int C) {
  __shared__ float tile[32][33];
  int z = blockIdx.z;
  int c0 = blockIdx.x * 32, r0 = blockIdx.y * 32;
  int tx = threadIdx.x, ty = threadIdx.y;
  size_t base = (size_t)z * R * C;
#pragma unroll
  for (int k = 0; k < 4; ++k)
    tile[ty + 8 * k][tx] =
        bf2f(src[base + (size_t)(r0 + ty + 8 * k) * C + c0 + tx]);
  __syncthreads();
#pragma unroll
  for (int k = 0; k < 4; ++k)
    dst[base + (size_t)(c0 + ty + 8 * k) * R + r0 + tx] = tile[tx][ty + 8 * k];
}

// ---------------- fp32 (R,C) -> bf16 (C,R) weight transpose ----------------
__global__ void tposebf(const float* __restrict__ src, ushort* __restrict__ dst,
                        int R, int C) {
  __shared__ float tile[32][33];
  int c0 = blockIdx.x * 32, r0 = blockIdx.y * 32;
  int tx = threadIdx.x, ty = threadIdx.y;
#pragma unroll
  for (int k = 0; k < 4; ++k)
    tile[ty + 8 * k][tx] = src[(size_t)(r0 + ty + 8 * k) * C + c0 + tx];
  __syncthreads();
#pragma unroll
  for (int k = 0; k < 4; ++k)
    dst[(size_t)(c0 + ty + 8 * k) * R + r0 + tx] = f2bf(tile[tx][ty + 8 * k]);
}

// ---------------- fast bf16 GEMM (activation x pre-transposed weight) ------
// C(Mr x N) = A(Mr x K) * B^T + epilogue.  B is bf16 (N x K) row-major.
// AMODE 0: A bf16.  AMODE 1: A fp32.
// OMODE 0: fp32 out (Cv, ldc).  OMODE 1: bf16 out (Cv, ldc).
// OMODE 2: split QKV: col<512 -> fp32 Cv (ldc); col>=512 -> bf16 Cv2 at
//          col-512 (ldc2).
// 2-deep register prefetch: load(t+2) issued while tile t computes; tile t+1
// regs written to LDS after the MFMA phase -> each load gets ~2 MFMA phases
// of latency cover.  XCD stripe swizzle when gridDim.y % 8 == 0.
template <int BN, int AMODE, int OMODE, bool BIAS, bool RES, bool GELU>
__global__ __launch_bounds__(256, 2) void bgemm(
    const void* __restrict__ Av, const ushort* __restrict__ Bh,
    const float* __restrict__ bias, const float* __restrict__ R,
    void* __restrict__ Cv, void* __restrict__ Cv2, int Mr, int K, int lda,
    int ldb, int ldr, int ldc, int ldc2) {
  constexpr int NJ = BN / 32;               // n-frags per wave
  constexpr int NBLD = (BN == 128) ? 4 : 2; // B uint4 loads per thread
  __shared__ ushort As[2][128 * 72];
  __shared__ ushort Bs[2][BN * 72];
  const ushort* Ah = (const ushort*)Av;
  const float* Af = (const float*)Av;
  int tid = threadIdx.x;
  int bx = blockIdx.x, by = blockIdx.y;
  if ((gridDim.y & 7) == 0) {
    int gx = gridDim.x, spx = gridDim.y >> 3;
    int flat = bx + by * gx;
    int c = flat & 7, t = flat >> 3;
    bx = t % gx;
    by = c * spx + t / gx;
  }
  int m0 = by * 128, n0 = bx * BN;
  int w = tid >> 6, lane = tid & 63;
  int ml = lane & 15, quad = lane >> 4;
  int m0w = (w & 1) * 64, n0w = (w >> 1) * (BN / 2);
  floatx4 acc[4][NJ];
#pragma unroll
  for (int i = 0; i < 4; ++i)
#pragma unroll
    for (int j = 0; j < NJ; ++j)
#pragma unroll
      for (int e = 0; e < 4; ++e) acc[i][j][e] = 0.f;

  int arow = tid >> 1, acol = (tid & 1) * 32;  // A: 2 thr/row, 32 ushorts each
  int brow = (BN == 128) ? (tid >> 1) : (tid >> 2);
  int bcol = (BN == 128) ? ((tid & 1) * 32) : ((tid & 3) * 16);
  uint4 ra0[4], rb0[NBLD], ra1[4], rb1[NBLD];

  auto loadAB = [&](int k0, uint4 (&ra)[4], uint4 (&rb)[NBLD]) {
    int garow = m0 + arow;
    if constexpr (AMODE == 0) {
      if (garow < Mr) {
        const uint4* p = (const uint4*)(Ah + (size_t)garow * lda + k0 + acol);
#pragma unroll
        for (int e = 0; e < 4; ++e) ra[e] = p[e];
      } else {
#pragma unroll
        for (int e = 0; e < 4; ++e) ra[e] = make_uint4(0u, 0u, 0u, 0u);
      }
    } else {
      if (garow < Mr) {
        const float4* p = (const float4*)(Af + (size_t)garow * lda + k0 + acol);
#pragma unroll
        for (int e = 0; e < 4; ++e) {
          float4 u0 = p[2 * e], u1 = p[2 * e + 1];
          ra[e] = make_uint4(pack2(u0.x, u0.y), pack2(u0.z, u0.w),
                             pack2(u1.x, u1.y), pack2(u1.z, u1.w));
        }
      } else {
#pragma unroll
        for (int e = 0; e < 4; ++e) ra[e] = make_uint4(0u, 0u, 0u, 0u);
      }
    }
    const uint4* pb = (const uint4*)(Bh + (size_t)(n0 + brow) * ldb + k0 + bcol);
#pragma unroll
    for (int e = 0; e < NBLD; ++e) rb[e] = pb[e];
  };
  auto writeAB = [&](int nb, const uint4 (&ra)[4], const uint4 (&rb)[NBLD]) {
    uint4* d = (uint4*)(As[nb] + arow * 72 + acol);
#pragma unroll
    for (int e = 0; e < 4; ++e) d[e] = ra[e];
    uint4* db = (uint4*)(Bs[nb] + brow * 72 + bcol);
#pragma unroll
    for (int e = 0; e < NBLD; ++e) db[e] = rb[e];
  };
  auto domfma = [&](const ushort* ca, const ushort* cb) {
#pragma unroll
    for (int kk = 0; kk < 2; ++kk) {
      short8 afr[4], bfr[NJ];
#pragma unroll
      for (int i = 0; i < 4; ++i)
        afr[i] = *(const short8*)(ca + (m0w + i * 16 + ml) * 72 + kk * 32 +
                                  quad * 8);
#pragma unroll
      for (int j = 0; j < NJ; ++j)
        bfr[j] = *(const short8*)(cb + (n0w + j * 16 + ml) * 72 + kk * 32 +
                                  quad * 8);
#pragma unroll
      for (int i = 0; i < 4; ++i)
#pragma unroll
        for (int j = 0; j < NJ; ++j)
          acc[i][j] = __builtin_amdgcn_mfma_f32_16x16x32_bf16(afr[i], bfr[j],
                                                              acc[i][j], 0, 0, 0);
    }
  };

  int nk = K >> 6;  // even, >= 8 for all our shapes
  loadAB(0, ra0, rb0);
  writeAB(0, ra0, rb0);
  loadAB(64, ra1, rb1);
  __syncthreads();
  int cur = 0;
  for (int t = 0; t < nk; t += 2) {
    if (t + 2 < nk) loadAB((t + 2) << 6, ra0, rb0);
    domfma(As[cur], Bs[cur]);
    writeAB(cur ^ 1, ra1, rb1);  // tile t+1
    __syncthreads();
    cur ^= 1;
    if (t + 3 < nk) loadAB((t + 3) << 6, ra1, rb1);
    domfma(As[cur], Bs[cur]);
    if (t + 2 < nk) writeAB(cur ^ 1, ra0, rb0);  // tile t+2
    __syncthreads();
    cur ^= 1;
  }
  // ---- epilogue ----
#pragma unroll
  for (int i = 0; i < 4; ++i)
#pragma unroll
    for (int r = 0; r < 4; ++r) {
      int row = m0 + m0w + i * 16 + quad * 4 + r;
      if (row < Mr) {
#pragma unroll
        for (int j = 0; j < NJ; ++j) {
          int col = n0 + n0w + j * 16 + ml;
          float v = acc[i][j][r];
          if (BIAS) v += bias[col];
          if (GELU) v = 0.5f * v * (1.0f + erff(v * 0.70710678f));
          if (RES) v += R[(size_t)row * ldr + col];
          if (OMODE == 0) {
            ((float*)Cv)[(size_t)row * ldc + col] = v;
          } else if (OMODE == 1) {
            ((ushort*)Cv)[(size_t)row * ldc + col] = f2bf(v);
          } else {
            if (col < 512)
              ((float*)Cv)[(size_t)row * ldc + col] = v;
            else
              ((ushort*)Cv2)[(size_t)row * ldc2 + col - 512] = f2bf(v);
          }
        }
      }
    }
}

// ---------------- t-attention (MFMA version) ----------------
// grid (N/128, B*H), block 256 = 4 waves; wave w owns 32 query rows.
// Q from gqxq fp32 (ld 512, split bf16 hi+lo); K/V from gqk fp32 (kx rows).
__global__ __launch_bounds__(256, 2) void tattn_kernel(
    const float* __restrict__ qx, const float* __restrict__ qk,
    const float* __restrict__ rdT, const float* __restrict__ mask,
    const float* __restrict__ kmask, ushort* __restrict__ sc,
    ushort* __restrict__ ao) {
  __shared__ ushort smA[256 * 72];
  __shared__ ushort Vt[64 * 264];
  __shared__ float kms[256];
  int bh = blockIdx.y, b = bh >> 3, h = bh & 7;
  int i00 = blockIdx.x * 128;
  int tid = threadIdx.x;
  // ---- stage K bf16 [j][d] stride 72, V^T bf16 [d][j] stride 264 ----
  {
    int jr = tid >> 2, c = tid & 3;
#pragma unroll
    for (int p = 0; p < 4; ++p) {
      int j = p * 64 + jr;
      const float* base = qk + (size_t)(b * 256 + j) * 1536 + h * 64 + c * 16;
      const float4* kp = (const float4*)(base + 512);
      float4 k0 = kp[0], k1 = kp[1], k2 = kp[2], k3 = kp[3];
      uint* kd = (uint*)(smA + j * 72 + c * 16);
      kd[0] = pack2(k0.x, k0.y); kd[1] = pack2(k0.z, k0.w);
      kd[2] = pack2(k1.x, k1.y); kd[3] = pack2(k1.z, k1.w);
      kd[4] = pack2(k2.x, k2.y); kd[5] = pack2(k2.z, k2.w);
      kd[6] = pack2(k3.x, k3.y); kd[7] = pack2(k3.z, k3.w);
      const float4* vp = (const float4*)(base + 1024);
      float4 v0 = vp[0], v1 = vp[1], v2 = vp[2], v3 = vp[3];
      float vv[16] = {v0.x, v0.y, v0.z, v0.w, v1.x, v1.y, v1.z, v1.w,
                      v2.x, v2.y, v2.z, v2.w, v3.x, v3.y, v3.z, v3.w};
#pragma unroll
      for (int e = 0; e < 16; ++e) Vt[(c * 16 + e) * 264 + j] = f2bf(vv[e]);
    }
  }
  kms[tid] = kmask[b * 256 + tid];

  int w = tid >> 6, lane = tid & 63, ml = lane & 15, quad = lane >> 4;
  int i0w = i00 + w * 32;
  short8 aqh[2][2], aql[2][2];
#pragma unroll
  for (int it = 0; it < 2; ++it) {
    const float* qrow =
        qx + (size_t)(b * 4096 + i0w + it * 16 + ml) * 512 + h * 64;
#pragma unroll
    for (int s = 0; s < 2; ++s) {
      const float4* qp = (const float4*)(qrow + s * 32 + quad * 8);
      float4 q0 = qp[0], q1 = qp[1];
      float qf[8] = {q0.x, q0.y, q0.z, q0.w, q1.x, q1.y, q1.z, q1.w};
      uint* ph = (uint*)&aqh[it][s];
      uint* pl = (uint*)&aql[it][s];
#pragma unroll
      for (int e = 0; e < 4; ++e) {
        ushort h0 = f2bf(qf[2 * e]), h1 = f2bf(qf[2 * e + 1]);
        float l0 = qf[2 * e] - __uint_as_float((uint)h0 << 16);
        float l1 = qf[2 * e + 1] - __uint_as_float((uint)h1 << 16);
        ph[e] = (uint)h0 | ((uint)h1 << 16);
        pl[e] = pack2(l0, l1);
      }
    }
  }

  floatx4 acc[2][16];
#pragma unroll
  for (int it = 0; it < 2; ++it)
#pragma unroll
    for (int jt = 0; jt < 16; ++jt)
#pragma unroll
      for (int e = 0; e < 4; ++e) acc[it][jt][e] = 0.f;
  __syncthreads();

#pragma unroll
  for (int jt = 0; jt < 16; ++jt) {
#pragma unroll
    for (int s = 0; s < 2; ++s) {
      short8 bk =
          *(const short8*)(smA + (jt * 16 + ml) * 72 + s * 32 + quad * 8);
      acc[0][jt] = __builtin_amdgcn_mfma_f32_16x16x32_bf16(aqh[0][s], bk,
                                                           acc[0][jt], 0, 0, 0);
      acc[1][jt] = __builtin_amdgcn_mfma_f32_16x16x32_bf16(aqh[1][s], bk,
                                                           acc[1][jt], 0, 0, 0);
      acc[0][jt] = __builtin_amdgcn_mfma_f32_16x16x32_bf16(aql[0][s], bk,
                                                           acc[0][jt], 0, 0, 0);
      acc[1][jt] = __builtin_amdgcn_mfma_f32_16x16x32_bf16(aql[1][s], bk,
                                                           acc[1][jt], 0, 0, 0);
    }
  }

#pragma unroll
  for (int it = 0; it < 2; ++it) {
#pragma unroll
    for (int r = 0; r < 4; ++r) {
      int i = i0w + it * 16 + quad * 4 + r;
      float mi = mask[b * 4096 + i];
      float mx = -3.0e38f;
#pragma unroll
      for (int jt = 0; jt < 16; ++jt) {
        float v = acc[it][jt][r] * 0.125f;
        v = (mi * kms[jt * 16 + ml] < 0.5f) ? NEGV : v;
        acc[it][jt][r] = v;
        mx = fmaxf(mx, v);
      }
      mx = fmaxf(mx, __shfl_xor(mx, 1));
      mx = fmaxf(mx, __shfl_xor(mx, 2));
      mx = fmaxf(mx, __shfl_xor(mx, 4));
      mx = fmaxf(mx, __shfl_xor(mx, 8));
      float Z = 0.f, Zs = 0.f;
#pragma unroll
      for (int jt = 0; jt < 16; ++jt) {
        float e = __expf(acc[it][jt][r] - mx);
        float e2 = e * e, e4 = e2 * e2, e8 = e4 * e4;
        acc[it][jt][r] = e;
        Z += e;
        Zs += e8 * e8 * e8;
      }
      Z += __shfl_xor(Z, 1); Z += __shfl_xor(Z, 2);
      Z += __shfl_xor(Z, 4); Z += __shfl_xor(Z, 8);
      Zs += __shfl_xor(Zs, 1); Zs += __shfl_xor(Zs, 2);
      Zs += __shfl_xor(Zs, 4); Zs += __shfl_xor(Zs, 8);
      float iZ = 1.f / Z, iZs = 1.f / Zs;
      const float* rrow = rdT + ((size_t)b * 4096 + i) * 256 + ml;
      ushort* srow = sc + ((size_t)bh * 4096 + i) * 256 + ml;
#pragma unroll
      for (int jt = 0; jt < 16; ++jt) {
        float e = acc[it][jt][r];
        float e2 = e * e, e4 = e2 * e2, e8 = e4 * e4;
        float rv = rrow[jt * 16];
        srow[jt * 16] = f2bf(e8 * e8 * e8 * iZs * rv);
        acc[it][jt][r] = e * iZ * rv;
      }
    }
  }

  floatx4 occ[2][4];
#pragma unroll
  for (int it = 0; it < 2; ++it)
#pragma unroll
    for (int n = 0; n < 4; ++n)
#pragma unroll
      for (int e = 0; e < 4; ++e) occ[it][n][e] = 0.f;
  ushort* Ps = smA;
#pragma unroll
  for (int ch = 0; ch < 2; ++ch) {
    __syncthreads();
#pragma unroll
    for (int it = 0; it < 2; ++it)
#pragma unroll
      for (int jj = 0; jj < 8; ++jj)
#pragma unroll
        for (int r = 0; r < 4; ++r)
          Ps[(w * 32 + it * 16 + quad * 4 + r) * 136 + jj * 16 + ml] =
              f2bf(acc[it][ch * 8 + jj][r]);
    __syncthreads();
#pragma unroll
    for (int ks = 0; ks < 4; ++ks) {
      short8 a0 = *(const short8*)(Ps + (w * 32 + ml) * 136 + ks * 32 + quad * 8);
      short8 a1 =
          *(const short8*)(Ps + (w * 32 + 16 + ml) * 136 + ks * 32 + quad * 8);
#pragma unroll
      for (int n = 0; n < 4; ++n) {
        short8 bv = *(const short8*)(Vt + (n * 16 + ml) * 264 + ch * 128 +
                                     ks * 32 + quad * 8);
        occ[0][n] =
            __builtin_amdgcn_mfma_f32_16x16x32_bf16(a0, bv, occ[0][n], 0, 0, 0);
        occ[1][n] =
            __builtin_amdgcn_mfma_f32_16x16x32_bf16(a1, bv, occ[1][n], 0, 0, 0);
      }
    }
  }
#pragma unroll
  for (int it = 0; it < 2; ++it)
#pragma unroll
    for (int r = 0; r < 4; ++r) {
      int i = i0w + it * 16 + quad * 4 + r;
      ushort* orow = ao + (size_t)(b * 4096 + i) * 512 + h * 64;
#pragma unroll
      for (int n = 0; n < 4; ++n) orow[n * 16 + ml] = f2bf(occ[it][n][r]);
    }
}

// ---------------- k-attention, fused flash-style ----------------
// q = k_q (gqk fp32, 256 rows), k/v = t_k/t_v from gkvh bf16 (4096 rows,
// row stride 1024: K at h*64, V at 512+h*64).  grid (16 j-chunks, 2 q-chunks,
// B*H).  Per chunk: local softmax partials (m, Z, Sum e*rd*v) -> pbuf.
__global__ __launch_bounds__(256, 2) void kattn_kernel(
    const float* __restrict__ qk, const ushort* __restrict__ kv,
    const float* __restrict__ rd, const float* __restrict__ mask,
    const float* __restrict__ kmask, float* __restrict__ pbuf) {
  __shared__ ushort smA[256 * 72];
  __shared__ ushort Vt[64 * 264];
  __shared__ float msk[256];
  int jc = blockIdx.x, qcb = blockIdx.y, bh = blockIdx.z;
  int b = bh >> 3, h = bh & 7;
  int j0 = jc * 256, i0b = qcb * 128;
  int tid = threadIdx.x;
  // ---- stage K bf16 [j][d] stride 72, V^T bf16 [d][j] stride 264 ----
  {
    int jr = tid >> 2, c = tid & 3;
#pragma unroll
    for (int p = 0; p < 4; ++p) {
      int j = p * 64 + jr;
      const ushort* base =
          kv + (size_t)(b * 4096 + j0 + j) * 1024 + h * 64 + c * 16;
      const uint4* kp = (const uint4*)base;
      uint4* kd = (uint4*)(smA + j * 72 + c * 16);
      kd[0] = kp[0];
      kd[1] = kp[1];
      ushort vv[16];
      *(uint4*)vv = ((const uint4*)(base + 512))[0];
      *(uint4*)(vv + 8) = ((const uint4*)(base + 512))[1];
#pragma unroll
      for (int e = 0; e < 16; ++e) Vt[(c * 16 + e) * 264 + j] = vv[e];
    }
  }
  msk[tid] = mask[b * 4096 + j0 + tid];

  int w = tid >> 6, lane = tid & 63, ml = lane & 15, quad = lane >> 4;
  int i0w = i0b + w * 32;
  // ---- Q (k_q) bf16 fragments straight from global ----
  short8 aq[2][2];
#pragma unroll
  for (int it = 0; it < 2; ++it) {
    const float* qrow =
        qk + (size_t)(b * 256 + i0w + it * 16 + ml) * 1536 + h * 64;
#pragma unroll
    for (int s = 0; s < 2; ++s) {
      const float4* qp = (const float4*)(qrow + s * 32 + quad * 8);
      float4 q0 = qp[0], q1 = qp[1];
      uint* ph = (uint*)&aq[it][s];
      ph[0] = pack2(q0.x, q0.y); ph[1] = pack2(q0.z, q0.w);
      ph[2] = pack2(q1.x, q1.y); ph[3] = pack2(q1.z, q1.w);
    }
  }

  floatx4 acc[2][16];
#pragma unroll
  for (int it = 0; it < 2; ++it)
#pragma unroll
    for (int jt = 0; jt < 16; ++jt)
#pragma unroll
      for (int e = 0; e < 4; ++e) acc[it][jt][e] = 0.f;
  __syncthreads();

#pragma unroll
  for (int jt = 0; jt < 16; ++jt) {
#pragma unroll
    for (int s = 0; s < 2; ++s) {
      short8 bk =
          *(const short8*)(smA + (jt * 16 + ml) * 72 + s * 32 + quad * 8);
      acc[0][jt] = __builtin_amdgcn_mfma_f32_16x16x32_bf16(aq[0][s], bk,
                                                           acc[0][jt], 0, 0, 0);
      acc[1][jt] = __builtin_amdgcn_mfma_f32_16x16x32_bf16(aq[1][s], bk,
                                                           acc[1][jt], 0, 0, 0);
    }
  }

  // ---- chunk-local softmax partials; P = e^{s-m} * rd ----
  float mrow[2][4], zrow[2][4];
#pragma unroll
  for (int it = 0; it < 2; ++it) {
#pragma unroll
    for (int r = 0; r < 4; ++r) {
      int i = i0w + it * 16 + quad * 4 + r;
      float kmq = kmask[b * 256 + i];
      float mx = -3.0e38f;
#pragma unroll
      for (int jt = 0; jt < 16; ++jt) {
        float v = acc[it][jt][r] * 0.125f;
        v = (msk[jt * 16 + ml] * kmq < 0.5f) ? NEGV : v;
        acc[it][jt][r] = v;
        mx = fmaxf(mx, v);
      }
      mx = fmaxf(mx, __shfl_xor(mx, 1));
      mx = fmaxf(mx, __shfl_xor(mx, 2));
      mx = fmaxf(mx, __shfl_xor(mx, 4));
      mx = fmaxf(mx, __shfl_xor(mx, 8));
      float Z = 0.f;
      const float* rrow = rd + (size_t)(b * 256 + i) * 4096 + j0 + ml;
#pragma unroll
      for (int jt = 0; jt < 16; ++jt) {
        float e = __expf(acc[it][jt][r] - mx);
        Z += e;
        acc[it][jt][r] = e * rrow[jt * 16];
      }
      Z += __shfl_xor(Z, 1); Z += __shfl_xor(Z, 2);
      Z += __shfl_xor(Z, 4); Z += __shfl_xor(Z, 8);
      mrow[it][r] = mx;
      zrow[it][r] = Z;
    }
  }

  // ---- PV: acc(128x256) @ V(256x64), two 128-col chunks via LDS ----
  floatx4 occ[2][4];
#pragma unroll
  for (int it = 0; it < 2; ++it)
#pragma unroll
    for (int n = 0; n < 4; ++n)
#pragma unroll
      for (int e = 0; e < 4; ++e) occ[it][n][e] = 0.f;
  ushort* Ps = smA;
#pragma unroll
  for (int ch = 0; ch < 2; ++ch) {
    __syncthreads();
#pragma unroll
    for (int it = 0; it < 2; ++it)
#pragma unroll
      for (int jj = 0; jj < 8; ++jj)
#pragma unroll
        for (int r = 0; r < 4; ++r)
          Ps[(w * 32 + it * 16 + quad * 4 + r) * 136 + jj * 16 + ml] =
              f2bf(acc[it][ch * 8 + jj][r]);
    __syncthreads();
#pragma unroll
    for (int ks = 0; ks < 4; ++ks) {
      short8 a0 = *(const short8*)(Ps + (w * 32 + ml) * 136 + ks * 32 + quad * 8);
      short8 a1 =
          *(const short8*)(Ps + (w * 32 + 16 + ml) * 136 + ks * 32 + quad * 8);
#pragma unroll
      for (int n = 0; n < 4; ++n) {
        short8 bv = *(const short8*)(Vt + (n * 16 + ml) * 264 + ch * 128 +
                                     ks * 32 + quad * 8);
        occ[0][n] =
            __builtin_amdgcn_mfma_f32_16x16x32_bf16(a0, bv, occ[0][n], 0, 0, 0);
        occ[1][n] =
            __builtin_amdgcn_mfma_f32_16x16x32_bf16(a1, bv, occ[1][n], 0, 0, 0);
      }
    }
  }
  // ---- write partials: 128 rows x (64 acc | m | Z) ----
  float* pb = pbuf + ((size_t)(bh * 2 + qcb) * 16 + jc) * (128 * 66);
#pragma unroll
  for (int it = 0; it < 2; ++it)
#pragma unroll
    for (int r = 0; r < 4; ++r) {
      int rowl = w * 32 + it * 16 + quad * 4 + r;
      float* prow = pb + rowl * 66;
#pragma unroll
      for (int n = 0; n < 4; ++n) prow[n * 16 + ml] = occ[it][n][r];
      if (ml == 0) {
        prow[64] = mrow[it][r];
        prow[65] = zrow[it][r];
      }
    }
}

// ---------------- k-attention combine (16 chunks -> k_out) ----------------
__global__ __launch_bounds__(256) void kcomb_kernel(
    const float* __restrict__ pbuf, float* __restrict__ ko) {
  int bq = blockIdx.x;  // 0..31
  int bh = bq >> 1, qcb = bq & 1;
  int b = bh >> 3, h = bh & 7;
  int tid = threadIdx.x;
  int row = tid >> 1, d0 = (tid & 1) * 32;
  const float* base = pbuf + ((size_t)(bh * 2 + qcb) * 16) * 8448 + row * 66;
  float mc[16], zc[16];
  float M = -3.0e38f;
#pragma unroll
  for (int c = 0; c < 16; ++c) {
    mc[c] = base[c * 8448 + 64];
    zc[c] = base[c * 8448 + 65];
    M = fmaxf(M, mc[c]);
  }
  float Zg = 0.f;
#pragma unroll
  for (int c = 0; c < 16; ++c) {
    mc[c] = __expf(mc[c] - M);
    Zg += zc[c] * mc[c];
  }
  float inv = 1.f / Zg;
  float o[32];
#pragma unroll
  for (int d = 0; d < 32; ++d) o[d] = 0.f;
#pragma unroll
  for (int c = 0; c < 16; ++c) {
    const float* pr = base + c * 8448 + d0;
    float wgt = mc[c];
#pragma unroll
    for (int d = 0; d < 32; ++d) o[d] = fmaf(pr[d], wgt, o[d]);
  }
  float* orow = ko + (size_t)(b * 256 + qcb * 128 + row) * 512 + h * 64 + d0;
#pragma unroll
  for (int d = 0; d < 32; ++d) orow[d] = o[d] * inv;
}

// ---------------- cls-token attention ----------------
__global__ __launch_bounds__(256) void cattn_kernel(
    const float* __restrict__ qc, const float* __restrict__ qk,
    const float* __restrict__ mask, const float* __restrict__ kmask,
    float* __restrict__ co) {
  __shared__ float q[64];
  __shared__ float p[256];
  __shared__ float red[4];
  __shared__ float part[4][64];
  int bh = blockIdx.x, b = bh >> 3, h = bh & 7;
  int tid = threadIdx.x;
  if (tid < 64) q[tid] = qc[(size_t)b * 1536 + h * 64 + tid];
  __syncthreads();
  float dot = 0.f;
  {
    const float* kr = qk + (size_t)(b * 256 + tid) * 1536 + 512 + h * 64;
#pragma unroll
    for (int d = 0; d < 64; ++d) dot = fmaf(q[d], kr[d], dot);
  }
  float mk = mask[b * 4096] * kmask[b * 256 + tid];
  dot = (mk < 0.5f) ? NEGV : dot * 0.125f;
  float mx = block_max(dot, red);
  float e = expf(dot - mx);
  float Z = block_sum(e, red);
  p[tid] = e / Z;
  __syncthreads();
  int d = tid & 63, s = tid >> 6;
  float acc = 0.f;
  for (int j = s * 64; j < s * 64 + 64; ++j)
    acc = fmaf(p[j], qk[(size_t)(b * 256 + j) * 1536 + 1024 + h * 64 + d], acc);
  part[s][d] = acc;
  __syncthreads();
  if (tid < 64)
    co[(size_t)b * 512 + h * 64 + tid] =
        part[0][tid] + part[1][tid] + part[2][tid] + part[3][tid];
}

__global__ void kreps_kernel(const float* __restrict__ kx,
                             const float* __restrict__ kmask,
                             float* __restrict__ o) {
  int idx = blockIdx.x * 256 + threadIdx.x;
  float km = kmask[idx >> 9];
  o[idx] = (km < 0.5f) ? 0.f : kx[idx];
}

__global__ void clcopy_kernel(const float* __restrict__ s,
                              float* __restrict__ o) {
  int idx = blockIdx.x * 256 + threadIdx.x;
  o[idx] = s[idx];
}

// ---------------- host launcher ----------------
extern "C" void kernel_launch(void* const* d_in, const int* in_sizes, int n_in,
                              void* d_out, int out_size, void* d_ws,
                              size_t ws_size, hipStream_t stream) {
  const float* x = (const float*)d_in[0];
  const float* kx = (const float*)d_in[1];
  const float* rd = (const float*)d_in[2];
  const float* clst = (const float*)d_in[3];
  const float* mask = (const float*)d_in[4];
  const float* kmask = (const float*)d_in[5];
  const float* ln0g = (const float*)d_in[6];
  const float* ln0b = (const float*)d_in[7];
  const float* qkvw = (const float*)d_in[8];
  const float* outw = (const float*)d_in[9];
  const float* outb = (const float*)d_in[10];
  const float* ln1g = (const float*)d_in[11];
  const float* ln1b = (const float*)d_in[12];
  const float* fw1 = (const float*)d_in[13];
  const float* fb1 = (const float*)d_in[14];
  const float* fw2 = (const float*)d_in[15];
  const float* fb2 = (const float*)d_in[16];
  float* out = (float*)d_out;

  float* buf = nullptr;
  hipGetSymbolAddress((void**)&buf, HIP_SYMBOL(g_buf));
  float* gx = buf + 0UL;
  float* glnx = buf + 4194304UL;
  float* gkx = buf + 8388608UL;
  float* glnk = buf + 8650752UL;
  float* gcl = buf + 8912896UL;
  float* glnc = buf + 8913920UL;
  float* gqxq = buf + 8914944UL;                     // fp32 Q (8192 x 512)
  ushort* gkvh = (ushort*)(buf + 13109248UL);        // bf16 KV (8192 x 1024)
  float* gqk = buf + 21497856UL;
  float* gqc = buf + 22284288UL;
  float* gko = buf + 26481664UL;
  float* gco = buf + 26743808UL;
  ushort* gsch = (ushort*)(buf + 26744832UL);        // bf16 sc (16,4096,256)
  float* gkd = buf + 43522048UL;
  float* gh = buf + 60299264UL;
  float* grdT = buf + 77076480UL;
  ushort* wts = (ushort*)(buf + 79173632UL);
  ushort* glnxh = (ushort*)(buf + 82319360UL);
  ushort* glnkh = (ushort*)(buf + 84416512UL);
  ushort* glnch = (ushort*)(buf + 84547584UL);
  ushort* gaoh = (ushort*)(buf + 84548096UL);
  ushort* ghh = (ushort*)gh;

  hipMemcpyAsync(gx, x, 4194304UL * 4, hipMemcpyDeviceToDevice, stream);
  hipMemcpyAsync(gkx, kx, 262144UL * 4, hipMemcpyDeviceToDevice, stream);
  hipMemcpyAsync(gcl, clst, 1024UL * 4, hipMemcpyDeviceToDevice, stream);

  // rd (b,256,4096) -> grdT (b,4096,256)
  tposef<<<dim3(128, 8, 2), dim3(32, 8, 1), 0, stream>>>(rd, grdT, 256, 4096);

  // weight convert+transpose: fp32 (K,N) -> bf16 (N,K)
  for (int l = 0; l < 2; ++l) {
    ushort* wtl = wts + (size_t)l * 3145728;
    tposebf<<<dim3(48, 16, 1), dim3(32, 8, 1), 0, stream>>>(
        qkvw + (size_t)l * 786432, wtl + 0, 512, 1536);
    tposebf<<<dim3(16, 16, 1), dim3(32, 8, 1), 0, stream>>>(
        outw + (size_t)l * 262144, wtl + 786432, 512, 512);
    tposebf<<<dim3(64, 16, 1), dim3(32, 8, 1), 0, stream>>>(
        fw1 + (size_t)l * 1048576, wtl + 1048576, 512, 2048);
    tposebf<<<dim3(16, 64, 1), dim3(32, 8, 1), 0, stream>>>(
        fw2 + (size_t)l * 1048576, wtl + 2097152, 2048, 512);
  }

  for (int l = 0; l < 2; ++l) {
    ushort* wtl = wts + (size_t)l * 3145728;
    ushort* qwt = wtl + 0;        // 1536 x 512
    ushort* owt = wtl + 786432;   // 512 x 512
    ushort* w1t = wtl + 1048576;  // 2048 x 512
    ushort* w2t = wtl + 2097152;  // 512 x 2048
    const float* ob = outb + (size_t)l * 512;
    const float* l0g = ln0g + l * 512;
    const float* l0b = ln0b + l * 512;
    const float* l1g = ln1g + l * 512;
    const float* l1b = ln1b + l * 512;
    const float* b1 = fb1 + (size_t)l * 2048;
    const float* b2 = fb2 + (size_t)l * 512;

    ln_kernel<<<8192, 256, 0, stream>>>(gx, glnx, glnxh, l0g, l0b);
    ln_kernel<<<512, 256, 0, stream>>>(gkx, glnk, glnkh, l0g, l0b);
    ln_kernel<<<2, 256, 0, stream>>>(gcl, glnc, glnch, l0g, l0b);

    // qkv projections: x -> Q fp32 + KV bf16 (split); kx/cl -> fp32
    bgemm<128, 0, 2, false, false, false>
        <<<dim3(12, 64, 1), 256, 0, stream>>>(glnxh, qwt, nullptr, nullptr,
                                              gqxq, gkvh, 8192, 512, 512, 512,
                                              0, 512, 1024);
    bgemm<128, 0, 0, false, false, false>
        <<<dim3(12, 4, 1), 256, 0, stream>>>(glnkh, qwt, nullptr, nullptr,
                                             gqk, nullptr, 512, 512, 512, 512,
                                             0, 1536, 0);
    bgemm<128, 0, 0, false, false, false>
        <<<dim3(12, 1, 1), 256, 0, stream>>>(glnch, qwt, nullptr, nullptr,
                                             gqc, nullptr, 2, 512, 512, 512,
                                             0, 1536, 0);

    tattn_kernel<<<dim3(32, 16, 1), 256, 0, stream>>>(gqxq, gqk, grdT, mask,
                                                      kmask, gsch, gaoh);
    cattn_kernel<<<16, 256, 0, stream>>>(gqc, gqk, mask, kmask, gco);

    // fused k-attention: partials + combine
    kattn_kernel<<<dim3(16, 2, 16), 256, 0, stream>>>(gqk, gkvh, rd, mask,
                                                      kmask, gkd);
    kcomb_kernel<<<32, 256, 0, stream>>>(gkd, gko);

    // to_out + residual
    bgemm<64, 0, 0, true, true, false>
        <<<dim3(8, 64, 1), 256, 0, stream>>>(gaoh, owt, ob, glnx, gx, nullptr,
                                             8192, 512, 512, 512, 512, 512, 0);
    bgemm<64, 1, 0, true, true, false>
        <<<dim3(8, 4, 1), 256, 0, stream>>>(gko, owt, ob, glnk, gkx, nullptr,
                                            512, 512, 512, 512, 512, 512, 0);
    bgemm<64, 1, 0, true, true, false>
        <<<dim3(8, 1, 1), 256, 0, stream>>>(gco, owt, ob, glnc, gcl, nullptr,
                                            2, 512, 512, 512, 512, 512, 0);

    // FF x  (ln1 fp32 copy is dead -> nullptr)
    ln_kernel<<<8192, 256, 0, stream>>>(gx, nullptr, glnxh, l1g, l1b);
    bgemm<128, 0, 1, true, false, true>
        <<<dim3(16, 64, 1), 256, 0, stream>>>(glnxh, w1t, b1, nullptr, ghh,
                                              nullptr, 8192, 512, 512, 512, 0,
                                              2048, 0);
    bgemm<64, 0, 0, true, true, false>
        <<<dim3(8, 64, 1), 256, 0, stream>>>(ghh, w2t, b2, gx, gx, nullptr,
                                             8192, 2048, 2048, 2048, 512, 512,
                                             0);
    // FF kx
    ln_kernel<<<512, 256, 0, stream>>>(gkx, nullptr, glnkh, l1g, l1b);
    bgemm<128, 0, 1, true, false, true>
        <<<dim3(16, 4, 1), 256, 0, stream>>>(glnkh, w1t, b1, nullptr, ghh,
                                             nullptr, 512, 512, 512, 512, 0,
                                             2048, 0);
    bgemm<64, 0, 0, true, true, false>
        <<<dim3(8, 4, 1), 256, 0, stream>>>(ghh, w2t, b2, gkx, gkx, nullptr,
                                            512, 2048, 2048, 2048, 512, 512,
                                            0);
    // FF clst
    ln_kernel<<<2, 256, 0, stream>>>(gcl, nullptr, glnch, l1g, l1b);
    bgemm<128, 0, 1, true, false, true>
        <<<dim3(16, 1, 1), 256, 0, stream>>>(glnch, w1t, b1, nullptr, ghh,
                                             nullptr, 2, 512, 512, 512, 0,
                                             2048, 0);
    bgemm<64, 0, 0, true, true, false>
        <<<dim3(8, 1, 1), 256, 0, stream>>>(ghh, w2t, b2, gcl, gcl, nullptr,
                                            2, 2048, 2048, 2048, 512, 512, 0);

    kreps_kernel<<<1024, 256, 0, stream>>>(gkx, kmask, out + (size_t)l * 262144);
    tposeh2f<<<dim3(8, 128, 16), dim3(32, 8, 1), 0, stream>>>(
        gsch, out + 525312UL + (size_t)l * 16777216UL, 4096, 256);
  }
  clcopy_kernel<<<4, 256, 0, stream>>>(gcl, out + 524288UL);
}

// Round 5
// 1000.587 us; speedup vs baseline: 1.4478x; 1.4478x over previous
//
#include <hip/hip_runtime.h>

typedef unsigned int uint;
typedef unsigned short ushort;
typedef __attribute__((ext_vector_type(8))) short short8;
typedef __attribute__((ext_vector_type(4))) float floatx4;

#define NEGV -1e9f

// ---------------- static scratch (compact, 179 MB) ----------------
// float offsets:
//  gx 0 (4194304) | glnx 4194304 | gqxq 8388608 (fp32 Q 8192x512)
//  gkvh 12582912 (bf16 KV 8192x1024 = 4194304 fl)
//  gsch 16777216 (bf16 sc (16,4096,256) = 8388608 fl)
//  gshare 25165824 (8388608 fl: ghh bf16 8192x2048 / gkd partials 4325376 fl)
//  grdT 33554432 (2097152) | wts 35651584 (6291456 us = 3145728 fl)
//  glnxh 38797312 (2097152 fl) | gaoh 40894464 (2097152 fl)
//  gkcl 42991616 (514x512 = 263168) | glnkcl 43254784 (263168)
//  gqkc 43517952 (514x1536 = 789504) | gkco 44307456 (263168)
//  glnkclh 44570624 (131584 fl)
__device__ float g_buf[44702208UL];

__device__ __forceinline__ ushort f2bf(float f) {
  uint u = __float_as_uint(f);
  u += 0x7fffu + ((u >> 16) & 1u);
  return (ushort)(u >> 16);
}
__device__ __forceinline__ uint pack2(float lo, float hi) {
  return (uint)f2bf(lo) | ((uint)f2bf(hi) << 16);
}
__device__ __forceinline__ float bf2f(ushort u) {
  return __uint_as_float((uint)u << 16);
}
// async global -> LDS, 16B per lane; LDS dest is wave-uniform base + lane*16
__device__ __forceinline__ void gload16(const void* g, void* l) {
  __builtin_amdgcn_global_load_lds(
      (const __attribute__((address_space(1))) void*)g,
      (__attribute__((address_space(3))) void*)l, 16, 0, 0);
}

// ---------------- reductions ----------------
__device__ __forceinline__ float wave_sum(float v) {
#pragma unroll
  for (int o = 1; o < 64; o <<= 1) v += __shfl_xor(v, o, 64);
  return v;
}
__device__ __forceinline__ float wave_max(float v) {
#pragma unroll
  for (int o = 1; o < 64; o <<= 1) v = fmaxf(v, __shfl_xor(v, o, 64));
  return v;
}
__device__ __forceinline__ float block_sum(float v, float* red) {
  v = wave_sum(v);
  if ((threadIdx.x & 63) == 0) red[threadIdx.x >> 6] = v;
  __syncthreads();
  float r = red[0] + red[1] + red[2] + red[3];
  __syncthreads();
  return r;
}
__device__ __forceinline__ float block_max(float v, float* red) {
  v = wave_max(v);
  if ((threadIdx.x & 63) == 0) red[threadIdx.x >> 6] = v;
  __syncthreads();
  float r = fmaxf(fmaxf(red[0], red[1]), fmaxf(red[2], red[3]));
  __syncthreads();
  return r;
}

// ---------------- LayerNorm (rows of 512), fp32 (optional) + bf16 out ------
__global__ __launch_bounds__(256) void ln_kernel(
    const float* __restrict__ in, float* __restrict__ out,
    ushort* __restrict__ outh, const float* __restrict__ gg,
    const float* __restrict__ bb) {
  __shared__ float red[4];
  size_t row = blockIdx.x;
  int tid = threadIdx.x;
  const float* p = in + row * 512;
  float v0 = p[tid], v1 = p[tid + 256];
  float mu = block_sum(v0 + v1, red) * (1.0f / 512.0f);
  float d0 = v0 - mu, d1 = v1 - mu;
  float var = block_sum(d0 * d0 + d1 * d1, red) * (1.0f / 512.0f);
  float rstd = rsqrtf(var + 1e-5f);
  float r0 = d0 * rstd * gg[tid] + bb[tid];
  float r1 = d1 * rstd * gg[tid + 256] + bb[tid + 256];
  if (out) {
    out[row * 512 + tid] = r0;
    out[row * 512 + tid + 256] = r1;
  }
  outh[row * 512 + tid] = f2bf(r0);
  outh[row * 512 + tid + 256] = f2bf(r1);
}

// ---------------- generic fp32 batched transpose ----------------
__global__ void tposef(const float* __restrict__ src, float* __restrict__ dst,
                       int R, int C) {
  __shared__ float tile[32][33];
  int z = blockIdx.z;
  int c0 = blockIdx.x * 32, r0 = blockIdx.y * 32;
  int tx = threadIdx.x, ty = threadIdx.y;
  size_t base = (size_t)z * R * C;
#pragma unroll
  for (int k = 0; k < 4; ++k)
    tile[ty + 8 * k][tx] = src[base + (size_t)(r0 + ty + 8 * k) * C + c0 + tx];
  __syncthreads();
#pragma unroll
  for (int k = 0; k < 4; ++k)
    dst[base + (size_t)(c0 + ty + 8 * k) * R + r0 + tx] = tile[tx][ty + 8 * k];
}

// ---------------- bf16 (Z,R,C) -> fp32 (Z,C,R) transpose (amaps) ----------
__global__ void tposeh2f(const ushort* __restrict__ src,
                         float* __restrict__ dst, int R, int C) {
  __shared__ float tile[32][33];
  int z = blockIdx.z;
  int c0 = blockIdx.x * 32, r0 = blockIdx.y * 32;
  int tx = threadIdx.x, ty = threadIdx.y;
  size_t base = (size_t)z * R * C;
#pragma unroll
  for (int k = 0; k < 4; ++k)
    tile[ty + 8 * k][tx] =
        bf2f(src[base + (size_t)(r0 + ty + 8 * k) * C + c0 + tx]);
  __syncthreads();
#pragma unroll
  for (int k = 0; k < 4; ++k)
    dst[base + (size_t)(c0 + ty + 8 * k) * R + r0 + tx] = tile[tx][ty + 8 * k];
}

// ---------------- fp32 (R,C) -> bf16 (C,R) weight transpose ----------------
__global__ void tposebf(const float* __restrict__ src, ushort* __restrict__ dst,
                        int R, int C) {
  __shared__ float tile[32][33];
  int c0 = blockIdx.x * 32, r0 = blockIdx.y * 32;
  int tx = threadIdx.x, ty = threadIdx.y;
#pragma unroll
  for (int k = 0; k < 4; ++k)
    tile[ty + 8 * k][tx] = src[(size_t)(r0 + ty + 8 * k) * C + c0 + tx];
  __syncthreads();
#pragma unroll
  for (int k = 0; k < 4; ++k)
    dst[(size_t)(c0 + ty + 8 * k) * R + r0 + tx] = f2bf(tile[tx][ty + 8 * k]);
}

// ---------------- fast bf16 GEMM (activation x pre-transposed weight) ------
// C(Mr x N) = A(Mr x K) * B^T + epilogue.  B is bf16 (N x K) row-major.
// AMODE 0: A bf16, staged via global_load_lds into linear [row][64] LDS with
//   T2 XOR swizzle (lds[r][s] = global[r][s ^ (r&7)], s = 16B slot);
//   ds_read applies the same XOR -> 2-way-free bank access.  One barrier per
//   BK=64 K-step (m97 structure).
// AMODE 1: A fp32, reg-staged with fp32->bf16 pack (small M only).
// OMODE 0: fp32 out.  OMODE 1: bf16 out.  OMODE 2: split QKV (col<512 fp32
//   Cv, col>=512 bf16 Cv2 at col-512).
// XCD stripe swizzle when gridDim.y % 8 == 0.
template <int BN, int AMODE, int OMODE, bool BIAS, bool RES, bool GELU>
__global__ __launch_bounds__(256, 2) void bgemm(
    const void* __restrict__ Av, const ushort* __restrict__ Bh,
    const float* __restrict__ bias, const float* __restrict__ R,
    void* __restrict__ Cv, void* __restrict__ Cv2, int Mr, int K, int lda,
    int ldb, int ldr, int ldc, int ldc2) {
  constexpr int NJ = BN / 32;  // n-frags per wave
  constexpr int ASTR = (AMODE == 0) ? 64 : 72;
  __shared__ ushort As[2][128 * ASTR];
  __shared__ ushort Bs[2][BN * ASTR];
  const ushort* Ah = (const ushort*)Av;
  const float* Af = (const float*)Av;
  int tid = threadIdx.x;
  int bx = blockIdx.x, by = blockIdx.y;
  if ((gridDim.y & 7) == 0) {
    int gx = gridDim.x, spx = gridDim.y >> 3;
    int flat = bx + by * gx;
    int c = flat & 7, t = flat >> 3;
    bx = t % gx;
    by = c * spx + t / gx;
  }
  int m0 = by * 128, n0 = bx * BN;
  int w = tid >> 6, lane = tid & 63;
  int ml = lane & 15, quad = lane >> 4;
  int m0w = (w & 1) * 64, n0w = (w >> 1) * (BN / 2);
  floatx4 acc[4][NJ];
#pragma unroll
  for (int i = 0; i < 4; ++i)
#pragma unroll
    for (int j = 0; j < NJ; ++j)
#pragma unroll
      for (int e = 0; e < 4; ++e) acc[i][j][e] = 0.f;

  int nk = K >> 6;

  if constexpr (AMODE == 0) {
    int lr = lane >> 3, lc = lane & 7;  // 8 rows x 8 slots per instruction
    auto stage = [&](int nb, int k0) {
      // A: 128 rows, wave w covers rows [w*32, w*32+32)
#pragma unroll
      for (int q = 0; q < 4; ++q) {
        int r = w * 32 + q * 8 + lr;
        int gr = m0 + r;
        gr = gr < Mr ? gr : Mr - 1;
        const ushort* gp = Ah + (size_t)gr * lda + k0 + ((lc ^ (r & 7)) << 3);
        gload16(gp, &As[nb][(w * 32 + q * 8) * 64]);
      }
      // B: BN rows, wave w covers rows [w*(BN/4), ...)
#pragma unroll
      for (int q = 0; q < BN / 32; ++q) {
        int r = w * (BN / 4) + q * 8 + lr;
        const ushort* gp =
            Bh + (size_t)(n0 + r) * ldb + k0 + ((lc ^ (r & 7)) << 3);
        gload16(gp, &Bs[nb][(w * (BN / 4) + q * 8) * 64]);
      }
    };
    stage(0, 0);
    __syncthreads();
    int cur = 0;
    for (int t = 0; t < nk; ++t) {
      if (t + 1 < nk) stage(cur ^ 1, (t + 1) << 6);
      const ushort* ca = As[cur];
      const ushort* cb = Bs[cur];
#pragma unroll
      for (int kk = 0; kk < 2; ++kk) {
        int soff = (((kk << 2) + quad) ^ (ml & 7)) << 3;
        short8 afr[4], bfr[NJ];
#pragma unroll
        for (int i = 0; i < 4; ++i)
          afr[i] = *(const short8*)(ca + (m0w + i * 16 + ml) * 64 + soff);
#pragma unroll
        for (int j = 0; j < NJ; ++j)
          bfr[j] = *(const short8*)(cb + (n0w + j * 16 + ml) * 64 + soff);
#pragma unroll
        for (int i = 0; i < 4; ++i)
#pragma unroll
          for (int j = 0; j < NJ; ++j)
            acc[i][j] = __builtin_amdgcn_mfma_f32_16x16x32_bf16(
                afr[i], bfr[j], acc[i][j], 0, 0, 0);
      }
      __syncthreads();
      cur ^= 1;
    }
  } else {
    // ---- reg-staged fp32-A path (small M) ----
    int arow = tid >> 1, acol = (tid & 1) * 32;
    int brow = (BN == 128) ? (tid >> 1) : (tid >> 2);
    int bcol = (BN == 128) ? ((tid & 1) * 32) : ((tid & 3) * 16);
    constexpr int NBLD = (BN == 128) ? 4 : 2;
    uint4 ra[4], rb[NBLD];
    auto loadAB = [&](int k0) {
      int garow = m0 + arow;
      if (garow < Mr) {
        const float4* p = (const float4*)(Af + (size_t)garow * lda + k0 + acol);
#pragma unroll
        for (int e = 0; e < 4; ++e) {
          float4 u0 = p[2 * e], u1 = p[2 * e + 1];
          ra[e] = make_uint4(pack2(u0.x, u0.y), pack2(u0.z, u0.w),
                             pack2(u1.x, u1.y), pack2(u1.z, u1.w));
        }
      } else {
#pragma unroll
        for (int e = 0; e < 4; ++e) ra[e] = make_uint4(0u, 0u, 0u, 0u);
      }
      const uint4* pb =
          (const uint4*)(Bh + (size_t)(n0 + brow) * ldb + k0 + bcol);
#pragma unroll
      for (int e = 0; e < NBLD; ++e) rb[e] = pb[e];
    };
    auto writeAB = [&](int nb) {
      uint4* d = (uint4*)(As[nb] + arow * 72 + acol);
#pragma unroll
      for (int e = 0; e < 4; ++e) d[e] = ra[e];
      uint4* db = (uint4*)(Bs[nb] + brow * 72 + bcol);
#pragma unroll
      for (int e = 0; e < NBLD; ++e) db[e] = rb[e];
    };
    loadAB(0);
    writeAB(0);
    __syncthreads();
    int cur = 0;
    for (int t = 0; t < nk; ++t) {
      if (t + 1 < nk) loadAB((t + 1) << 6);
      const ushort* ca = As[cur];
      const ushort* cb = Bs[cur];
#pragma unroll
      for (int kk = 0; kk < 2; ++kk) {
        short8 afr[4], bfr[NJ];
#pragma unroll
        for (int i = 0; i < 4; ++i)
          afr[i] = *(const short8*)(ca + (m0w + i * 16 + ml) * 72 + kk * 32 +
                                    quad * 8);
#pragma unroll
        for (int j = 0; j < NJ; ++j)
          bfr[j] = *(const short8*)(cb + (n0w + j * 16 + ml) * 72 + kk * 32 +
                                    quad * 8);
#pragma unroll
        for (int i = 0; i < 4; ++i)
#pragma unroll
          for (int j = 0; j < NJ; ++j)
            acc[i][j] = __builtin_amdgcn_mfma_f32_16x16x32_bf16(
                afr[i], bfr[j], acc[i][j], 0, 0, 0);
      }
      if (t + 1 < nk) writeAB(cur ^ 1);
      __syncthreads();
      cur ^= 1;
    }
  }
  // ---- epilogue ----
#pragma unroll
  for (int i = 0; i < 4; ++i)
#pragma unroll
    for (int r = 0; r < 4; ++r) {
      int row = m0 + m0w + i * 16 + quad * 4 + r;
      if (row < Mr) {
#pragma unroll
        for (int j = 0; j < NJ; ++j) {
          int col = n0 + n0w + j * 16 + ml;
          float v = acc[i][j][r];
          if (BIAS) v += bias[col];
          if (GELU) v = 0.5f * v * (1.0f + erff(v * 0.70710678f));
          if (RES) v += R[(size_t)row * ldr + col];
          if (OMODE == 0) {
            ((float*)Cv)[(size_t)row * ldc + col] = v;
          } else if (OMODE == 1) {
            ((ushort*)Cv)[(size_t)row * ldc + col] = f2bf(v);
          } else {
            if (col < 512)
              ((float*)Cv)[(size_t)row * ldc + col] = v;
            else
              ((ushort*)Cv2)[(size_t)row * ldc2 + col - 512] = f2bf(v);
          }
        }
      }
    }
}

// ---------------- t-attention (MFMA version) ----------------
// grid (N/128, B*H), block 256 = 4 waves; wave w owns 32 query rows.
// Q from gqxq fp32 (ld 512, split bf16 hi+lo); K/V from gqkc fp32 (kx rows).
__global__ __launch_bounds__(256, 2) void tattn_kernel(
    const float* __restrict__ qx, const float* __restrict__ qk,
    const float* __restrict__ rdT, const float* __restrict__ mask,
    const float* __restrict__ kmask, ushort* __restrict__ sc,
    ushort* __restrict__ ao) {
  __shared__ ushort smA[256 * 72];
  __shared__ ushort Vt[64 * 264];
  __shared__ float kms[256];
  int bh = blockIdx.y, b = bh >> 3, h = bh & 7;
  int i00 = blockIdx.x * 128;
  int tid = threadIdx.x;
  {
    int jr = tid >> 2, c = tid & 3;
#pragma unroll
    for (int p = 0; p < 4; ++p) {
      int j = p * 64 + jr;
      const float* base = qk + (size_t)(b * 256 + j) * 1536 + h * 64 + c * 16;
      const float4* kp = (const float4*)(base + 512);
      float4 k0 = kp[0], k1 = kp[1], k2 = kp[2], k3 = kp[3];
      uint* kd = (uint*)(smA + j * 72 + c * 16);
      kd[0] = pack2(k0.x, k0.y); kd[1] = pack2(k0.z, k0.w);
      kd[2] = pack2(k1.x, k1.y); kd[3] = pack2(k1.z, k1.w);
      kd[4] = pack2(k2.x, k2.y); kd[5] = pack2(k2.z, k2.w);
      kd[6] = pack2(k3.x, k3.y); kd[7] = pack2(k3.z, k3.w);
      const float4* vp = (const float4*)(base + 1024);
      float4 v0 = vp[0], v1 = vp[1], v2 = vp[2], v3 = vp[3];
      float vv[16] = {v0.x, v0.y, v0.z, v0.w, v1.x, v1.y, v1.z, v1.w,
                      v2.x, v2.y, v2.z, v2.w, v3.x, v3.y, v3.z, v3.w};
#pragma unroll
      for (int e = 0; e < 16; ++e) Vt[(c * 16 + e) * 264 + j] = f2bf(vv[e]);
    }
  }
  kms[tid] = kmask[b * 256 + tid];

  int w = tid >> 6, lane = tid & 63, ml = lane & 15, quad = lane >> 4;
  int i0w = i00 + w * 32;
  short8 aqh[2][2], aql[2][2];
#pragma unroll
  for (int it = 0; it < 2; ++it) {
    const float* qrow =
        qx + (size_t)(b * 4096 + i0w + it * 16 + ml) * 512 + h * 64;
#pragma unroll
    for (int s = 0; s < 2; ++s) {
      const float4* qp = (const float4*)(qrow + s * 32 + quad * 8);
      float4 q0 = qp[0], q1 = qp[1];
      float qf[8] = {q0.x, q0.y, q0.z, q0.w, q1.x, q1.y, q1.z, q1.w};
      uint* ph = (uint*)&aqh[it][s];
      uint* pl = (uint*)&aql[it][s];
#pragma unroll
      for (int e = 0; e < 4; ++e) {
        ushort h0 = f2bf(qf[2 * e]), h1 = f2bf(qf[2 * e + 1]);
        float l0 = qf[2 * e] - __uint_as_float((uint)h0 << 16);
        float l1 = qf[2 * e + 1] - __uint_as_float((uint)h1 << 16);
        ph[e] = (uint)h0 | ((uint)h1 << 16);
        pl[e] = pack2(l0, l1);
      }
    }
  }

  floatx4 acc[2][16];
#pragma unroll
  for (int it = 0; it < 2; ++it)
#pragma unroll
    for (int jt = 0; jt < 16; ++jt)
#pragma unroll
      for (int e = 0; e < 4; ++e) acc[it][jt][e] = 0.f;
  __syncthreads();

#pragma unroll
  for (int jt = 0; jt < 16; ++jt) {
#pragma unroll
    for (int s = 0; s < 2; ++s) {
      short8 bk =
          *(const short8*)(smA + (jt * 16 + ml) * 72 + s * 32 + quad * 8);
      acc[0][jt] = __builtin_amdgcn_mfma_f32_16x16x32_bf16(aqh[0][s], bk,
                                                           acc[0][jt], 0, 0, 0);
      acc[1][jt] = __builtin_amdgcn_mfma_f32_16x16x32_bf16(aqh[1][s], bk,
                                                           acc[1][jt], 0, 0, 0);
      acc[0][jt] = __builtin_amdgcn_mfma_f32_16x16x32_bf16(aql[0][s], bk,
                                                           acc[0][jt], 0, 0, 0);
      acc[1][jt] = __builtin_amdgcn_mfma_f32_16x16x32_bf16(aql[1][s], bk,
                                                           acc[1][jt], 0, 0, 0);
    }
  }

#pragma unroll
  for (int it = 0; it < 2; ++it) {
#pragma unroll
    for (int r = 0; r < 4; ++r) {
      int i = i0w + it * 16 + quad * 4 + r;
      float mi = mask[b * 4096 + i];
      float mx = -3.0e38f;
#pragma unroll
      for (int jt = 0; jt < 16; ++jt) {
        float v = acc[it][jt][r] * 0.125f;
        v = (mi * kms[jt * 16 + ml] < 0.5f) ? NEGV : v;
        acc[it][jt][r] = v;
        mx = fmaxf(mx, v);
      }
      mx = fmaxf(mx, __shfl_xor(mx, 1));
      mx = fmaxf(mx, __shfl_xor(mx, 2));
      mx = fmaxf(mx, __shfl_xor(mx, 4));
      mx = fmaxf(mx, __shfl_xor(mx, 8));
      float Z = 0.f, Zs = 0.f;
#pragma unroll
      for (int jt = 0; jt < 16; ++jt) {
        float e = __expf(acc[it][jt][r] - mx);
        float e2 = e * e, e4 = e2 * e2, e8 = e4 * e4;
        acc[it][jt][r] = e;
        Z += e;
        Zs += e8 * e8 * e8;
      }
      Z += __shfl_xor(Z, 1); Z += __shfl_xor(Z, 2);
      Z += __shfl_xor(Z, 4); Z += __shfl_xor(Z, 8);
      Zs += __shfl_xor(Zs, 1); Zs += __shfl_xor(Zs, 2);
      Zs += __shfl_xor(Zs, 4); Zs += __shfl_xor(Zs, 8);
      float iZ = 1.f / Z, iZs = 1.f / Zs;
      const float* rrow = rdT + ((size_t)b * 4096 + i) * 256 + ml;
      ushort* srow = sc + ((size_t)bh * 4096 + i) * 256 + ml;
#pragma unroll
      for (int jt = 0; jt < 16; ++jt) {
        float e = acc[it][jt][r];
        float e2 = e * e, e4 = e2 * e2, e8 = e4 * e4;
        float rv = rrow[jt * 16];
        srow[jt * 16] = f2bf(e8 * e8 * e8 * iZs * rv);
        acc[it][jt][r] = e * iZ * rv;
      }
    }
  }

  floatx4 occ[2][4];
#pragma unroll
  for (int it = 0; it < 2; ++it)
#pragma unroll
    for (int n = 0; n < 4; ++n)
#pragma unroll
      for (int e = 0; e < 4; ++e) occ[it][n][e] = 0.f;
  ushort* Ps = smA;
#pragma unroll
  for (int ch = 0; ch < 2; ++ch) {
    __syncthreads();
#pragma unroll
    for (int it = 0; it < 2; ++it)
#pragma unroll
      for (int jj = 0; jj < 8; ++jj)
#pragma unroll
        for (int r = 0; r < 4; ++r)
          Ps[(w * 32 + it * 16 + quad * 4 + r) * 136 + jj * 16 + ml] =
              f2bf(acc[it][ch * 8 + jj][r]);
    __syncthreads();
#pragma unroll
    for (int ks = 0; ks < 4; ++ks) {
      short8 a0 = *(const short8*)(Ps + (w * 32 + ml) * 136 + ks * 32 + quad * 8);
      short8 a1 =
          *(const short8*)(Ps + (w * 32 + 16 + ml) * 136 + ks * 32 + quad * 8);
#pragma unroll
      for (int n = 0; n < 4; ++n) {
        short8 bv = *(const short8*)(Vt + (n * 16 + ml) * 264 + ch * 128 +
                                     ks * 32 + quad * 8);
        occ[0][n] =
            __builtin_amdgcn_mfma_f32_16x16x32_bf16(a0, bv, occ[0][n], 0, 0, 0);
        occ[1][n] =
            __builtin_amdgcn_mfma_f32_16x16x32_bf16(a1, bv, occ[1][n], 0, 0, 0);
      }
    }
  }
#pragma unroll
  for (int it = 0; it < 2; ++it)
#pragma unroll
    for (int r = 0; r < 4; ++r) {
      int i = i0w + it * 16 + quad * 4 + r;
      ushort* orow = ao + (size_t)(b * 4096 + i) * 512 + h * 64;
#pragma unroll
      for (int n = 0; n < 4; ++n) orow[n * 16 + ml] = f2bf(occ[it][n][r]);
    }
}

// ---------------- k-attention, fused flash-style ----------------
__global__ __launch_bounds__(256, 2) void kattn_kernel(
    const float* __restrict__ qk, const ushort* __restrict__ kv,
    const float* __restrict__ rd, const float* __restrict__ mask,
    const float* __restrict__ kmask, float* __restrict__ pbuf) {
  __shared__ ushort smA[256 * 72];
  __shared__ ushort Vt[64 * 264];
  __shared__ float msk[256];
  int jc = blockIdx.x, qcb = blockIdx.y, bh = blockIdx.z;
  int b = bh >> 3, h = bh & 7;
  int j0 = jc * 256, i0b = qcb * 128;
  int tid = threadIdx.x;
  {
    int jr = tid >> 2, c = tid & 3;
#pragma unroll
    for (int p = 0; p < 4; ++p) {
      int j = p * 64 + jr;
      const ushort* base =
          kv + (size_t)(b * 4096 + j0 + j) * 1024 + h * 64 + c * 16;
      const uint4* kp = (const uint4*)base;
      uint4* kd = (uint4*)(smA + j * 72 + c * 16);
      kd[0] = kp[0];
      kd[1] = kp[1];
      ushort vv[16];
      *(uint4*)vv = ((const uint4*)(base + 512))[0];
      *(uint4*)(vv + 8) = ((const uint4*)(base + 512))[1];
#pragma unroll
      for (int e = 0; e < 16; ++e) Vt[(c * 16 + e) * 264 + j] = vv[e];
    }
  }
  msk[tid] = mask[b * 4096 + j0 + tid];

  int w = tid >> 6, lane = tid & 63, ml = lane & 15, quad = lane >> 4;
  int i0w = i0b + w * 32;
  short8 aq[2][2];
#pragma unroll
  for (int it = 0; it < 2; ++it) {
    const float* qrow =
        qk + (size_t)(b * 256 + i0w + it * 16 + ml) * 1536 + h * 64;
#pragma unroll
    for (int s = 0; s < 2; ++s) {
      const float4* qp = (const float4*)(qrow + s * 32 + quad * 8);
      float4 q0 = qp[0], q1 = qp[1];
      uint* ph = (uint*)&aq[it][s];
      ph[0] = pack2(q0.x, q0.y); ph[1] = pack2(q0.z, q0.w);
      ph[2] = pack2(q1.x, q1.y); ph[3] = pack2(q1.z, q1.w);
    }
  }

  floatx4 acc[2][16];
#pragma unroll
  for (int it = 0; it < 2; ++it)
#pragma unroll
    for (int jt = 0; jt < 16; ++jt)
#pragma unroll
      for (int e = 0; e < 4; ++e) acc[it][jt][e] = 0.f;
  __syncthreads();

#pragma unroll
  for (int jt = 0; jt < 16; ++jt) {
#pragma unroll
    for (int s = 0; s < 2; ++s) {
      short8 bk =
          *(const short8*)(smA + (jt * 16 + ml) * 72 + s * 32 + quad * 8);
      acc[0][jt] = __builtin_amdgcn_mfma_f32_16x16x32_bf16(aq[0][s], bk,
                                                           acc[0][jt], 0, 0, 0);
      acc[1][jt] = __builtin_amdgcn_mfma_f32_16x16x32_bf16(aq[1][s], bk,
                                                           acc[1][jt], 0, 0, 0);
    }
  }

  float mrow[2][4], zrow[2][4];
#pragma unroll
  for (int it = 0; it < 2; ++it) {
#pragma unroll
    for (int r = 0; r < 4; ++r) {
      int i = i0w + it * 16 + quad * 4 + r;
      float kmq = kmask[b * 256 + i];
      float mx = -3.0e38f;
#pragma unroll
      for (int jt = 0; jt < 16; ++jt) {
        float v = acc[it][jt][r] * 0.125f;
        v = (msk[jt * 16 + ml] * kmq < 0.5f) ? NEGV : v;
        acc[it][jt][r] = v;
        mx = fmaxf(mx, v);
      }
      mx = fmaxf(mx, __shfl_xor(mx, 1));
      mx = fmaxf(mx, __shfl_xor(mx, 2));
      mx = fmaxf(mx, __shfl_xor(mx, 4));
      mx = fmaxf(mx, __shfl_xor(mx, 8));
      float Z = 0.f;
      const float* rrow = rd + (size_t)(b * 256 + i) * 4096 + j0 + ml;
#pragma unroll
      for (int jt = 0; jt < 16; ++jt) {
        float e = __expf(acc[it][jt][r] - mx);
        Z += e;
        acc[it][jt][r] = e * rrow[jt * 16];
      }
      Z += __shfl_xor(Z, 1); Z += __shfl_xor(Z, 2);
      Z += __shfl_xor(Z, 4); Z += __shfl_xor(Z, 8);
      mrow[it][r] = mx;
      zrow[it][r] = Z;
    }
  }

  floatx4 occ[2][4];
#pragma unroll
  for (int it = 0; it < 2; ++it)
#pragma unroll
    for (int n = 0; n < 4; ++n)
#pragma unroll
      for (int e = 0; e < 4; ++e) occ[it][n][e] = 0.f;
  ushort* Ps = smA;
#pragma unroll
  for (int ch = 0; ch < 2; ++ch) {
    __syncthreads();
#pragma unroll
    for (int it = 0; it < 2; ++it)
#pragma unroll
      for (int jj = 0; jj < 8; ++jj)
#pragma unroll
        for (int r = 0; r < 4; ++r)
          Ps[(w * 32 + it * 16 + quad * 4 + r) * 136 + jj * 16 + ml] =
              f2bf(acc[it][ch * 8 + jj][r]);
    __syncthreads();
#pragma unroll
    for (int ks = 0; ks < 4; ++ks) {
      short8 a0 = *(const short8*)(Ps + (w * 32 + ml) * 136 + ks * 32 + quad * 8);
      short8 a1 =
          *(const short8*)(Ps + (w * 32 + 16 + ml) * 136 + ks * 32 + quad * 8);
#pragma unroll
      for (int n = 0; n < 4; ++n) {
        short8 bv = *(const short8*)(Vt + (n * 16 + ml) * 264 + ch * 128 +
                                     ks * 32 + quad * 8);
        occ[0][n] =
            __builtin_amdgcn_mfma_f32_16x16x32_bf16(a0, bv, occ[0][n], 0, 0, 0);
        occ[1][n] =
            __builtin_amdgcn_mfma_f32_16x16x32_bf16(a1, bv, occ[1][n], 0, 0, 0);
      }
    }
  }
  float* pb = pbuf + ((size_t)(bh * 2 + qcb) * 16 + jc) * (128 * 66);
#pragma unroll
  for (int it = 0; it < 2; ++it)
#pragma unroll
    for (int r = 0; r < 4; ++r) {
      int rowl = w * 32 + it * 16 + quad * 4 + r;
      float* prow = pb + rowl * 66;
#pragma unroll
      for (int n = 0; n < 4; ++n) prow[n * 16 + ml] = occ[it][n][r];
      if (ml == 0) {
        prow[64] = mrow[it][r];
        prow[65] = zrow[it][r];
      }
    }
}

// ---------------- k-attention combine (16 chunks -> k_out) ----------------
__global__ __launch_bounds__(256) void kcomb_kernel(
    const float* __restrict__ pbuf, float* __restrict__ ko) {
  int bq = blockIdx.x;  // 0..31
  int bh = bq >> 1, qcb = bq & 1;
  int b = bh >> 3, h = bh & 7;
  int tid = threadIdx.x;
  int row = tid >> 1, d0 = (tid & 1) * 32;
  const float* base = pbuf + ((size_t)(bh * 2 + qcb) * 16) * 8448 + row * 66;
  float mc[16], zc[16];
  float M = -3.0e38f;
#pragma unroll
  for (int c = 0; c < 16; ++c) {
    mc[c] = base[c * 8448 + 64];
    zc[c] = base[c * 8448 + 65];
    M = fmaxf(M, mc[c]);
  }
  float Zg = 0.f;
#pragma unroll
  for (int c = 0; c < 16; ++c) {
    mc[c] = __expf(mc[c] - M);
    Zg += zc[c] * mc[c];
  }
  float inv = 1.f / Zg;
  float o[32];
#pragma unroll
  for (int d = 0; d < 32; ++d) o[d] = 0.f;
#pragma unroll
  for (int c = 0; c < 16; ++c) {
    const float* pr = base + c * 8448 + d0;
    float wgt = mc[c];
#pragma unroll
    for (int d = 0; d < 32; ++d) o[d] = fmaf(pr[d], wgt, o[d]);
  }
  float* orow = ko + (size_t)(b * 256 + qcb * 128 + row) * 512 + h * 64 + d0;
#pragma unroll
  for (int d = 0; d < 32; ++d) orow[d] = o[d] * inv;
}

// ---------------- cls-token attention ----------------
__global__ __launch_bounds__(256) void cattn_kernel(
    const float* __restrict__ qc, const float* __restrict__ qk,
    const float* __restrict__ mask, const float* __restrict__ kmask,
    float* __restrict__ co) {
  __shared__ float q[64];
  __shared__ float p[256];
  __shared__ float red[4];
  __shared__ float part[4][64];
  int bh = blockIdx.x, b = bh >> 3, h = bh & 7;
  int tid = threadIdx.x;
  if (tid < 64) q[tid] = qc[(size_t)b * 1536 + h * 64 + tid];
  __syncthreads();
  float dot = 0.f;
  {
    const float* kr = qk + (size_t)(b * 256 + tid) * 1536 + 512 + h * 64;
#pragma unroll
    for (int d = 0; d < 64; ++d) dot = fmaf(q[d], kr[d], dot);
  }
  float mk = mask[b * 4096] * kmask[b * 256 + tid];
  dot = (mk < 0.5f) ? NEGV : dot * 0.125f;
  float mx = block_max(dot, red);
  float e = expf(dot - mx);
  float Z = block_sum(e, red);
  p[tid] = e / Z;
  __syncthreads();
  int d = tid & 63, s = tid >> 6;
  float acc = 0.f;
  for (int j = s * 64; j < s * 64 + 64; ++j)
    acc = fmaf(p[j], qk[(size_t)(b * 256 + j) * 1536 + 1024 + h * 64 + d], acc);
  part[s][d] = acc;
  __syncthreads();
  if (tid < 64)
    co[(size_t)b * 512 + h * 64 + tid] =
        part[0][tid] + part[1][tid] + part[2][tid] + part[3][tid];
}

__global__ void kreps_kernel(const float* __restrict__ kx,
                             const float* __restrict__ kmask,
                             float* __restrict__ o) {
  int idx = blockIdx.x * 256 + threadIdx.x;
  float km = kmask[idx >> 9];
  o[idx] = (km < 0.5f) ? 0.f : kx[idx];
}

__global__ void clcopy_kernel(const float* __restrict__ s,
                              float* __restrict__ o) {
  int idx = blockIdx.x * 256 + threadIdx.x;
  o[idx] = s[idx];
}

// ---------------- host launcher ----------------
extern "C" void kernel_launch(void* const* d_in, const int* in_sizes, int n_in,
                              void* d_out, int out_size, void* d_ws,
                              size_t ws_size, hipStream_t stream) {
  const float* x = (const float*)d_in[0];
  const float* kx = (const float*)d_in[1];
  const float* rd = (const float*)d_in[2];
  const float* clst = (const float*)d_in[3];
  const float* mask = (const float*)d_in[4];
  const float* kmask = (const float*)d_in[5];
  const float* ln0g = (const float*)d_in[6];
  const float* ln0b = (const float*)d_in[7];
  const float* qkvw = (const float*)d_in[8];
  const float* outw = (const float*)d_in[9];
  const float* outb = (const float*)d_in[10];
  const float* ln1g = (const float*)d_in[11];
  const float* ln1b = (const float*)d_in[12];
  const float* fw1 = (const float*)d_in[13];
  const float* fb1 = (const float*)d_in[14];
  const float* fw2 = (const float*)d_in[15];
  const float* fb2 = (const float*)d_in[16];
  float* out = (float*)d_out;

  float* buf = nullptr;
  hipGetSymbolAddress((void**)&buf, HIP_SYMBOL(g_buf));
  float* gx = buf + 0UL;
  float* glnx = buf + 4194304UL;
  float* gqxq = buf + 8388608UL;                   // fp32 Q (8192 x 512)
  ushort* gkvh = (ushort*)(buf + 12582912UL);      // bf16 KV (8192 x 1024)
  ushort* gsch = (ushort*)(buf + 16777216UL);      // bf16 sc (16,4096,256)
  float* gshare = buf + 25165824UL;                // gkd partials / ghh
  ushort* ghh = (ushort*)gshare;                   // bf16 hidden (8192 x 2048)
  float* grdT = buf + 33554432UL;
  ushort* wts = (ushort*)(buf + 35651584UL);
  ushort* glnxh = (ushort*)(buf + 38797312UL);
  ushort* gaoh = (ushort*)(buf + 40894464UL);
  float* gkcl = buf + 42991616UL;                  // kx(512) + cl(2) rows
  float* glnkcl = buf + 43254784UL;
  float* gqkc = buf + 43517952UL;                  // QKV out 514 x 1536
  float* gkco = buf + 44307456UL;                  // attn out 514 x 512
  ushort* glnkclh = (ushort*)(buf + 44570624UL);

  hipMemcpyAsync(gx, x, 4194304UL * 4, hipMemcpyDeviceToDevice, stream);
  hipMemcpyAsync(gkcl, kx, 262144UL * 4, hipMemcpyDeviceToDevice, stream);
  hipMemcpyAsync(gkcl + 262144UL, clst, 1024UL * 4, hipMemcpyDeviceToDevice,
                 stream);

  // rd (b,256,4096) -> grdT (b,4096,256)
  tposef<<<dim3(128, 8, 2), dim3(32, 8, 1), 0, stream>>>(rd, grdT, 256, 4096);

  // weight convert+transpose: fp32 (K,N) -> bf16 (N,K)
  for (int l = 0; l < 2; ++l) {
    ushort* wtl = wts + (size_t)l * 3145728;
    tposebf<<<dim3(48, 16, 1), dim3(32, 8, 1), 0, stream>>>(
        qkvw + (size_t)l * 786432, wtl + 0, 512, 1536);
    tposebf<<<dim3(16, 16, 1), dim3(32, 8, 1), 0, stream>>>(
        outw + (size_t)l * 262144, wtl + 786432, 512, 512);
    tposebf<<<dim3(64, 16, 1), dim3(32, 8, 1), 0, stream>>>(
        fw1 + (size_t)l * 1048576, wtl + 1048576, 512, 2048);
    tposebf<<<dim3(16, 64, 1), dim3(32, 8, 1), 0, stream>>>(
        fw2 + (size_t)l * 1048576, wtl + 2097152, 2048, 512);
  }

  for (int l = 0; l < 2; ++l) {
    ushort* wtl = wts + (size_t)l * 3145728;
    ushort* qwt = wtl + 0;        // 1536 x 512
    ushort* owt = wtl + 786432;   // 512 x 512
    ushort* w1t = wtl + 1048576;  // 2048 x 512
    ushort* w2t = wtl + 2097152;  // 512 x 2048
    const float* ob = outb + (size_t)l * 512;
    const float* l0g = ln0g + l * 512;
    const float* l0b = ln0b + l * 512;
    const float* l1g = ln1g + l * 512;
    const float* l1b = ln1b + l * 512;
    const float* b1 = fb1 + (size_t)l * 2048;
    const float* b2 = fb2 + (size_t)l * 512;

    ln_kernel<<<8192, 256, 0, stream>>>(gx, glnx, glnxh, l0g, l0b);
    ln_kernel<<<514, 256, 0, stream>>>(gkcl, glnkcl, glnkclh, l0g, l0b);

    // qkv projections: x -> Q fp32 + KV bf16 (split); kcl -> fp32
    bgemm<128, 0, 2, false, false, false>
        <<<dim3(12, 64, 1), 256, 0, stream>>>(glnxh, qwt, nullptr, nullptr,
                                              gqxq, gkvh, 8192, 512, 512, 512,
                                              0, 512, 1024);
    bgemm<128, 0, 0, false, false, false>
        <<<dim3(12, 5, 1), 256, 0, stream>>>(glnkclh, qwt, nullptr, nullptr,
                                             gqkc, nullptr, 514, 512, 512, 512,
                                             0, 1536, 0);

    tattn_kernel<<<dim3(32, 16, 1), 256, 0, stream>>>(gqxq, gqkc, grdT, mask,
                                                      kmask, gsch, gaoh);
    cattn_kernel<<<16, 256, 0, stream>>>(gqkc + 786432UL, gqkc, mask, kmask,
                                         gkco + 262144UL);

    // fused k-attention: partials + combine
    kattn_kernel<<<dim3(16, 2, 16), 256, 0, stream>>>(gqkc, gkvh, rd, mask,
                                                      kmask, gshare);
    kcomb_kernel<<<32, 256, 0, stream>>>(gshare, gkco);

    // to_out + residual
    bgemm<64, 0, 0, true, true, false>
        <<<dim3(8, 64, 1), 256, 0, stream>>>(gaoh, owt, ob, glnx, gx, nullptr,
                                             8192, 512, 512, 512, 512, 512, 0);
    bgemm<64, 1, 0, true, true, false>
        <<<dim3(8, 5, 1), 256, 0, stream>>>(gkco, owt, ob, glnkcl, gkcl,
                                            nullptr, 514, 512, 512, 512, 512,
                                            512, 0);

    // FF x
    ln_kernel<<<8192, 256, 0, stream>>>(gx, nullptr, glnxh, l1g, l1b);
    bgemm<128, 0, 1, true, false, true>
        <<<dim3(16, 64, 1), 256, 0, stream>>>(glnxh, w1t, b1, nullptr, ghh,
                                              nullptr, 8192, 512, 512, 512, 0,
                                              2048, 0);
    bgemm<64, 0, 0, true, true, false>
        <<<dim3(8, 64, 1), 256, 0, stream>>>(ghh, w2t, b2, gx, gx, nullptr,
                                             8192, 2048, 2048, 2048, 512, 512,
                                             0);
    // FF kcl
    ln_kernel<<<514, 256, 0, stream>>>(gkcl, nullptr, glnkclh, l1g, l1b);
    bgemm<128, 0, 1, true, false, true>
        <<<dim3(16, 5, 1), 256, 0, stream>>>(glnkclh, w1t, b1, nullptr, ghh,
                                             nullptr, 514, 512, 512, 512, 0,
                                             2048, 0);
    bgemm<64, 0, 0, true, true, false>
        <<<dim3(8, 5, 1), 256, 0, stream>>>(ghh, w2t, b2, gkcl, gkcl, nullptr,
                                            514, 2048, 2048, 2048, 512, 512,
                                            0);

    kreps_kernel<<<1024, 256, 0, stream>>>(gkcl, kmask,
                                           out + (size_t)l * 262144);
    tposeh2f<<<dim3(8, 128, 16), dim3(32, 8, 1), 0, stream>>>(
        gsch, out + 525312UL + (size_t)l * 16777216UL, 4096, 256);
  }
  clcopy_kernel<<<4, 256, 0, stream>>>(gkcl + 262144UL, out + 524288UL);
}